// Round 2
// baseline (80813.153 us; speedup 1.0000x reference)
//
#include <hip/hip_runtime.h>
#include <hip/hip_bf16.h>

#define TT 512
#define BB 64
#define DD 2048
#define LL 4
#define VV 64

typedef unsigned short u16;
typedef unsigned int u32;
typedef __attribute__((ext_vector_type(8))) short s16x8;
typedef __attribute__((ext_vector_type(4))) float f32x4;

// RNE float->bf16 (no NaN handling needed; all values finite & bounded)
__device__ inline u16 f2b(float f) {
  u32 u = __builtin_bit_cast(u32, f);
  u32 r = (u + 0x7fffu + ((u >> 16) & 1u)) >> 16;
  return (u16)r;
}

__device__ inline s16x8 cvt8(const float* p) {
  f32x4 f0 = *(const f32x4*)p;
  f32x4 f1 = *(const f32x4*)(p + 4);
  s16x8 r;
  r[0] = (short)f2b(f0[0]); r[1] = (short)f2b(f0[1]);
  r[2] = (short)f2b(f0[2]); r[3] = (short)f2b(f0[3]);
  r[4] = (short)f2b(f1[0]); r[5] = (short)f2b(f1[1]);
  r[6] = (short)f2b(f1[2]); r[7] = (short)f2b(f1[3]);
  return r;
}

__global__ __launch_bounds__(256) void convert_w(const float* __restrict__ src,
                                                 u16* __restrict__ dst, size_t n4) {
  size_t i = (size_t)blockIdx.x * 256 + threadIdx.x;
  size_t stride = (size_t)gridDim.x * 256;
  for (size_t j = i; j < n4; j += stride) {
    float4 f = ((const float4*)src)[j];
    ushort4 o;
    o.x = f2b(f.x); o.y = f2b(f.y); o.z = f2b(f.z); o.w = f2b(f.w);
    ((ushort4*)dst)[j] = o;
  }
}

// output projection for one timestep: out[b, tout, :] = Hf3[b,:] @ Wout + bout
// called by 8 blocks (bx = 0..7), 256 threads each
__device__ inline void out_proj(const float* __restrict__ Hprev_f,
                                const float* __restrict__ Wout,
                                const float* __restrict__ bout,
                                float* __restrict__ out,
                                int tout, int bx, int tid, float* red) {
  const int v = tid & 63, kg = tid >> 6;  // 64 vocab cols x 4 k-groups of 512
  const float* Hf3 = Hprev_f + (size_t)3 * BB * DD;
  for (int bb = 0; bb < 8; ++bb) {
    int b = bx * 8 + bb;
    const float* hp = Hf3 + (size_t)b * DD + kg * 512;
    const float* wp = Wout + (size_t)(kg * 512) * VV + v;
    float s = 0.f;
#pragma unroll 8
    for (int k = 0; k < 512; ++k) s = fmaf(hp[k], wp[(size_t)k * VV], s);
    red[tid] = s;
    __syncthreads();
    if (tid < 64) {
      float r = red[tid] + red[tid + 64] + red[tid + 128] + red[tid + 192] + bout[v];
      out[((size_t)b * TT + tout) * VV + v] = r;
    }
    __syncthreads();
  }
}

// One timestep: grid (64, 5). y<4: layer blocks (32 output cols each).
// y==4, x<8: output projection of step t-1 (state already in Hprev).
__global__ __launch_bounds__(256)
void rnn_step(int t,
              const int* __restrict__ ids, const int* __restrict__ slen,
              const float* __restrict__ emb,
              const float* __restrict__ bx, const float* __restrict__ bh,
              const u16* __restrict__ Wxb, const u16* __restrict__ Whb,
              const float* __restrict__ Hprev_f, float* __restrict__ Hcur_f,
              const u16* __restrict__ Hprev_b, u16* __restrict__ Hcur_b,
              const float* __restrict__ Wout, const float* __restrict__ bout,
              float* __restrict__ out) {
  const int tid = threadIdx.x;
  const int l = blockIdx.y;

  if (l == LL) {
    if (t == 0 || blockIdx.x >= 8) return;
    __shared__ float red[256];
    out_proj(Hprev_f, Wout, bout, out, t - 1, blockIdx.x, tid, red);
    return;
  }

  // ---- layer block: computes pre[b, n0..n0+31] for 64 batch rows ----
  const int n0 = blockIdx.x * 32;
  const int wave = tid >> 6, lane = tid & 63;
  const int mh = wave & 1, nh = wave >> 1;       // 2x2 wave tiling: 32 rows x 16 cols
  const int lr = lane & 15, lk = (lane >> 4) * 8;
  const int ncol = n0 + nh * 16 + lr;            // weight row (output col)

  const u16* w0 = Wxb + ((size_t)l * DD + ncol) * DD + lk;
  const u16* w1 = Whb + ((size_t)l * DD + ncol) * DD + lk;

  const int brow0 = mh * 32 + lr;   // m-tile 0 batch row for A-frag
  const int brow1 = brow0 + 16;     // m-tile 1

  const u16* a1p0 = Hprev_b + ((size_t)(l * BB + brow0)) * DD + lk;
  const u16* a1p1 = Hprev_b + ((size_t)(l * BB + brow1)) * DD + lk;

  f32x4 acc0 = {0.f, 0.f, 0.f, 0.f}, acc1 = {0.f, 0.f, 0.f, 0.f};

  if (l == 0) {
    const float* e0 = emb + (size_t)ids[brow0 * TT + t] * DD + lk;
    const float* e1 = emb + (size_t)ids[brow1 * TT + t] * DD + lk;
#pragma unroll 4
    for (int kb = 0; kb < DD; kb += 32) {
      s16x8 b0 = *(const s16x8*)(w0 + kb);
      s16x8 b1 = *(const s16x8*)(w1 + kb);
      s16x8 a00 = cvt8(e0 + kb);
      s16x8 a01 = cvt8(e1 + kb);
      s16x8 a10 = *(const s16x8*)(a1p0 + kb);
      s16x8 a11 = *(const s16x8*)(a1p1 + kb);
      acc0 = __builtin_amdgcn_mfma_f32_16x16x32_bf16(a00, b0, acc0, 0, 0, 0);
      acc0 = __builtin_amdgcn_mfma_f32_16x16x32_bf16(a10, b1, acc0, 0, 0, 0);
      acc1 = __builtin_amdgcn_mfma_f32_16x16x32_bf16(a01, b0, acc1, 0, 0, 0);
      acc1 = __builtin_amdgcn_mfma_f32_16x16x32_bf16(a11, b1, acc1, 0, 0, 0);
    }
  } else {
    const u16* a0p0 = Hprev_b + ((size_t)((l - 1) * BB + brow0)) * DD + lk;
    const u16* a0p1 = Hprev_b + ((size_t)((l - 1) * BB + brow1)) * DD + lk;
#pragma unroll 4
    for (int kb = 0; kb < DD; kb += 32) {
      s16x8 b0 = *(const s16x8*)(w0 + kb);
      s16x8 b1 = *(const s16x8*)(w1 + kb);
      s16x8 a00 = *(const s16x8*)(a0p0 + kb);
      s16x8 a01 = *(const s16x8*)(a0p1 + kb);
      s16x8 a10 = *(const s16x8*)(a1p0 + kb);
      s16x8 a11 = *(const s16x8*)(a1p1 + kb);
      acc0 = __builtin_amdgcn_mfma_f32_16x16x32_bf16(a00, b0, acc0, 0, 0, 0);
      acc0 = __builtin_amdgcn_mfma_f32_16x16x32_bf16(a10, b1, acc0, 0, 0, 0);
      acc1 = __builtin_amdgcn_mfma_f32_16x16x32_bf16(a01, b0, acc1, 0, 0, 0);
      acc1 = __builtin_amdgcn_mfma_f32_16x16x32_bf16(a11, b1, acc1, 0, 0, 0);
    }
  }

  // epilogue: bias, tanh, mask, write fp32 master + bf16 copy
  const float bsum = bx[l * DD + ncol] + bh[l * DD + ncol];
  const int rbase = (lane >> 4) * 4;
#pragma unroll
  for (int i = 0; i < 4; ++i) {
    int b0r = mh * 32 + rbase + i;
    int b1r = b0r + 16;
    float h0 = tanhf(acc0[i] + bsum);
    float h1 = tanhf(acc1[i] + bsum);
    size_t i0 = ((size_t)(l * BB + b0r)) * DD + ncol;
    size_t i1 = ((size_t)(l * BB + b1r)) * DD + ncol;
    float v0 = (t < slen[b0r]) ? h0 : Hprev_f[i0];
    float v1 = (t < slen[b1r]) ? h1 : Hprev_f[i1];
    Hcur_f[i0] = v0;
    Hcur_f[i1] = v1;
    Hcur_b[i0] = f2b(v0);
    Hcur_b[i1] = f2b(v1);
  }
}

__global__ __launch_bounds__(256)
void final_out(const float* __restrict__ Hf, const float* __restrict__ Wout,
               const float* __restrict__ bout, float* __restrict__ out) {
  __shared__ float red[256];
  out_proj(Hf, Wout, bout, out, TT - 1, blockIdx.x, threadIdx.x, red);
}

extern "C" void kernel_launch(void* const* d_in, const int* in_sizes, int n_in,
                              void* d_out, int out_size, void* d_ws, size_t ws_size,
                              hipStream_t stream) {
  const int* ids = (const int*)d_in[0];
  const int* slen = (const int*)d_in[1];
  const float* emb = (const float*)d_in[2];
  const float* Wx = (const float*)d_in[3];
  const float* bx = (const float*)d_in[4];
  const float* Wh = (const float*)d_in[5];
  const float* bh = (const float*)d_in[6];
  const float* Wout = (const float*)d_in[7];
  const float* bout = (const float*)d_in[8];
  float* out = (float*)d_out;

  char* ws = (char*)d_ws;
  const size_t oW = (size_t)LL * DD * DD * 2;   // bf16 weight array bytes
  const size_t oH = (size_t)LL * BB * DD * 4;   // fp32 state bytes
  const size_t oHb = (size_t)LL * BB * DD * 2;  // bf16 state bytes
  u16* Wxb = (u16*)ws;
  u16* Whb = (u16*)(ws + oW);
  float* Hf0 = (float*)(ws + 2 * oW);
  float* Hf1 = (float*)(ws + 2 * oW + oH);
  u16* Hb0 = (u16*)(ws + 2 * oW + 2 * oH);
  u16* Hb1 = (u16*)(ws + 2 * oW + 2 * oH + oHb);

  // zero initial state (both buffers, f32 + bf16)
  hipMemsetAsync(ws + 2 * oW, 0, 2 * oH + 2 * oHb, stream);

  const size_t n4 = (size_t)LL * DD * DD / 4;
  convert_w<<<dim3(4096), dim3(256), 0, stream>>>(Wx, Wxb, n4);
  convert_w<<<dim3(4096), dim3(256), 0, stream>>>(Wh, Whb, n4);

  for (int t = 0; t < TT; ++t) {
    const float* pf = (t & 1) ? Hf1 : Hf0;
    float* cf = (t & 1) ? Hf0 : Hf1;
    const u16* pb = (t & 1) ? Hb1 : Hb0;
    u16* cb = (t & 1) ? Hb0 : Hb1;
    rnn_step<<<dim3(64, 5), dim3(256), 0, stream>>>(
        t, ids, slen, emb, bx, bh, Wxb, Whb, pf, cf, pb, cb, Wout, bout, out);
  }
  // state(511) lives in Hf0 (t=511 odd wrote cf=Hf0)
  final_out<<<dim3(8), dim3(256), 0, stream>>>(Hf0, Wout, bout, out);
}

// Round 3
// 30157.672 us; speedup vs baseline: 2.6797x; 2.6797x over previous
//
#include <hip/hip_runtime.h>
#include <hip/hip_bf16.h>

#define TT 512
#define BB 64
#define DD 2048
#define LL 4
#define VV 64

typedef unsigned short u16;
typedef unsigned int u32;
typedef __attribute__((ext_vector_type(8))) short s16x8;
typedef __attribute__((ext_vector_type(4))) float f32x4;

#define MFMA(a, b, c) __builtin_amdgcn_mfma_f32_16x16x32_bf16((a), (b), (c), 0, 0, 0)

__device__ inline u16 f2b(float f) {
  u32 u = __builtin_bit_cast(u32, f);
  u32 r = (u + 0x7fffu + ((u >> 16) & 1u)) >> 16;
  return (u16)r;
}
__device__ inline float b2f(u16 b) {
  u32 u = ((u32)b) << 16;
  return __builtin_bit_cast(float, u);
}
__device__ inline s16x8 cvt8(const float* p) {
  f32x4 f0 = *(const f32x4*)p;
  f32x4 f1 = *(const f32x4*)(p + 4);
  s16x8 r;
  r[0] = (short)f2b(f0[0]); r[1] = (short)f2b(f0[1]);
  r[2] = (short)f2b(f0[2]); r[3] = (short)f2b(f0[3]);
  r[4] = (short)f2b(f1[0]); r[5] = (short)f2b(f1[1]);
  r[6] = (short)f2b(f1[2]); r[7] = (short)f2b(f1[3]);
  return r;
}

__global__ __launch_bounds__(256) void convert_w(const float* __restrict__ src,
                                                 u16* __restrict__ dst, size_t n4) {
  size_t i = (size_t)blockIdx.x * 256 + threadIdx.x;
  size_t stride = (size_t)gridDim.x * 256;
  for (size_t j = i; j < n4; j += stride) {
    float4 f = ((const float4*)src)[j];
    ushort4 o;
    o.x = f2b(f.x); o.y = f2b(f.y); o.z = f2b(f.z); o.w = f2b(f.w);
    ((ushort4*)dst)[j] = o;
  }
}

// WoutT[v][k] = bf16(Wout[k][v]);  Wout is [2048][64] fp32
__global__ __launch_bounds__(256) void convert_woT(const float* __restrict__ Wout,
                                                   u16* __restrict__ WoT) {
  int g = blockIdx.x * 256 + threadIdx.x;  // 131072 total
  int v = g >> 11, k = g & 2047;
  WoT[(size_t)v * DD + k] = f2b(Wout[(size_t)k * VV + v]);
}

// Persistent kernel: 256 blocks x 512 threads, one block per CU.
// Block bid -> layer l = bid>>6, columns col0 = (bid&63)*32.
// 8 waves: ch = w&1 (16-col half), ks = w>>2? no: ks = w>>1 (k-slice of 512).
// Weights held in VGPRs (32 x s16x8 per lane = 128 VGPRs).
__global__ __launch_bounds__(512, 2)
void persist(const int* __restrict__ ids, const int* __restrict__ slen,
             const float* __restrict__ emb,
             const float* __restrict__ bxp, const float* __restrict__ bhp,
             const u16* __restrict__ Wxb, const u16* __restrict__ Whb,
             const u16* __restrict__ WoT, const float* __restrict__ bout,
             u16* __restrict__ HbA, u16* __restrict__ HbB,
             float* __restrict__ out, int* __restrict__ cnt) {
  const int tid = threadIdx.x, bid = blockIdx.x;
  const int l = bid >> 6;
  const int col0 = (bid & 63) << 5;
  const int w = tid >> 6, lane = tid & 63;
  const int ch = w & 1, ks = w >> 1;
  const int lr = lane & 15, q = lane >> 4;
  const int ncol = col0 + (ch << 4) + lr;
  const int kb0 = (ks << 9) + (q << 3);  // ks*512 + q*8

  // ---- load weight fragments into VGPRs (once) ----
  s16x8 wx[16], wh[16];
  {
    const u16* p0 = Wxb + ((size_t)l * DD + ncol) * DD + kb0;
    const u16* p1 = Whb + ((size_t)l * DD + ncol) * DD + kb0;
#pragma unroll
    for (int kt = 0; kt < 16; ++kt) {
      wx[kt] = *(const s16x8*)(p0 + (kt << 5));
      wh[kt] = *(const s16x8*)(p1 + (kt << 5));
    }
  }

  // ---- out-proj assignment: 4 batch rows x 4 vocab cols per block ----
  const int opo = tid >> 5, ln32 = tid & 31;
  const int opb = ((bid >> 4) << 2) + (opo >> 2);
  const int opv = ((bid & 15) << 2) + (opo & 3);
  const float boutv = bout[opv];

  // ---- per-thread reduce-output precompute (4 outputs each) ----
  int rm[4], rn[4], rcol[4], rch[4], rslen[4];
  float bsum[4];
#pragma unroll
  for (int s = 0; s < 4; ++s) {
    int o = tid + (s << 9);
    int cch = o >> 10, rem = o & 1023;
    rm[s] = rem >> 4;
    rn[s] = rem & 15;
    rch[s] = cch;
    rcol[s] = col0 + (cch << 4) + rn[s];
    bsum[s] = bxp[l * DD + rcol[s]] + bhp[l * DD + rcol[s]];
    rslen[s] = slen[rm[s]];
  }

  __shared__ float part[8][64][17];
  __shared__ int sids[64];

  const u16* Hp = HbA;
  u16* Hc = HbB;
  int ep = 0;

  for (int t = 0; t <= TT; ++t) {
    if (t < TT) {
      if (tid < BB) sids[tid] = ids[tid * TT + t];
      __syncthreads();

      f32x4 acc0 = {0, 0, 0, 0}, acc1 = {0, 0, 0, 0};
      f32x4 acc2 = {0, 0, 0, 0}, acc3 = {0, 0, 0, 0};
      const u16* hsrc = Hp + (size_t)l * BB * DD;
      if (l == 0) {
#pragma unroll
        for (int kt = 0; kt < 16; ++kt) {
          const int kk = kb0 + (kt << 5);
          s16x8 ax0 = cvt8(emb + (size_t)sids[lr] * DD + kk);
          s16x8 ax1 = cvt8(emb + (size_t)sids[lr + 16] * DD + kk);
          s16x8 ax2 = cvt8(emb + (size_t)sids[lr + 32] * DD + kk);
          s16x8 ax3 = cvt8(emb + (size_t)sids[lr + 48] * DD + kk);
          s16x8 ah0 = *(const s16x8*)(hsrc + (size_t)lr * DD + kk);
          s16x8 ah1 = *(const s16x8*)(hsrc + (size_t)(lr + 16) * DD + kk);
          s16x8 ah2 = *(const s16x8*)(hsrc + (size_t)(lr + 32) * DD + kk);
          s16x8 ah3 = *(const s16x8*)(hsrc + (size_t)(lr + 48) * DD + kk);
          acc0 = MFMA(ax0, wx[kt], acc0); acc0 = MFMA(ah0, wh[kt], acc0);
          acc1 = MFMA(ax1, wx[kt], acc1); acc1 = MFMA(ah1, wh[kt], acc1);
          acc2 = MFMA(ax2, wx[kt], acc2); acc2 = MFMA(ah2, wh[kt], acc2);
          acc3 = MFMA(ax3, wx[kt], acc3); acc3 = MFMA(ah3, wh[kt], acc3);
        }
      } else {
        const u16* xsrc = Hp + (size_t)(l - 1) * BB * DD;
#pragma unroll
        for (int kt = 0; kt < 16; ++kt) {
          const int kk = kb0 + (kt << 5);
          s16x8 ax0 = *(const s16x8*)(xsrc + (size_t)lr * DD + kk);
          s16x8 ax1 = *(const s16x8*)(xsrc + (size_t)(lr + 16) * DD + kk);
          s16x8 ax2 = *(const s16x8*)(xsrc + (size_t)(lr + 32) * DD + kk);
          s16x8 ax3 = *(const s16x8*)(xsrc + (size_t)(lr + 48) * DD + kk);
          s16x8 ah0 = *(const s16x8*)(hsrc + (size_t)lr * DD + kk);
          s16x8 ah1 = *(const s16x8*)(hsrc + (size_t)(lr + 16) * DD + kk);
          s16x8 ah2 = *(const s16x8*)(hsrc + (size_t)(lr + 32) * DD + kk);
          s16x8 ah3 = *(const s16x8*)(hsrc + (size_t)(lr + 48) * DD + kk);
          acc0 = MFMA(ax0, wx[kt], acc0); acc0 = MFMA(ah0, wh[kt], acc0);
          acc1 = MFMA(ax1, wx[kt], acc1); acc1 = MFMA(ah1, wh[kt], acc1);
          acc2 = MFMA(ax2, wx[kt], acc2); acc2 = MFMA(ah2, wh[kt], acc2);
          acc3 = MFMA(ax3, wx[kt], acc3); acc3 = MFMA(ah3, wh[kt], acc3);
        }
      }
      // partials to LDS: part[w][m][n], m = mt*16 + q*4 + i, n = lr
#pragma unroll
      for (int i = 0; i < 4; ++i) {
        part[w][(q << 2) + i][lr] = acc0[i];
        part[w][16 + (q << 2) + i][lr] = acc1[i];
        part[w][32 + (q << 2) + i][lr] = acc2[i];
        part[w][48 + (q << 2) + i][lr] = acc3[i];
      }
      __syncthreads();
      // k-reduction + bias + tanh + mask + state write (4 outputs/thread)
#pragma unroll
      for (int s = 0; s < 4; ++s) {
        const int cch = rch[s], m = rm[s], n = rn[s];
        float sum = part[cch][m][n] + part[cch + 2][m][n] +
                    part[cch + 4][m][n] + part[cch + 6][m][n] + bsum[s];
        float hv = tanhf(sum);
        size_t idx = ((size_t)l * BB + m) * DD + rcol[s];
        Hc[idx] = (t < rslen[s]) ? f2b(hv) : Hp[idx];
      }
    }

    // output projection for step t-1 (reads Hp = state t-1)
    if (t > 0) {
      const u16* h3 = Hp + (size_t)3 * BB * DD;
      const u16* hp = h3 + (size_t)opb * DD + (ln32 << 6);
      const u16* wp = WoT + (size_t)opv * DD + (ln32 << 6);
      float sacc = 0.f;
#pragma unroll
      for (int j = 0; j < 64; j += 8) {
        s16x8 hv8 = *(const s16x8*)(hp + j);
        s16x8 wv8 = *(const s16x8*)(wp + j);
#pragma unroll
        for (int e = 0; e < 8; ++e)
          sacc = fmaf(b2f((u16)hv8[e]), b2f((u16)wv8[e]), sacc);
      }
#pragma unroll
      for (int d = 16; d > 0; d >>= 1) sacc += __shfl_xor(sacc, d, 64);
      if (ln32 == 0)
        out[((size_t)opb * TT + (t - 1)) * VV + opv] = sacc + boutv;
    }

    // grid sync (custom, agent-scope), then swap state buffers
    if (t < TT) {
      ++ep;
      __syncthreads();
      if (tid == 0) {
        __hip_atomic_fetch_add(cnt, 1, __ATOMIC_RELEASE, __HIP_MEMORY_SCOPE_AGENT);
        const int target = ep << 8;  // 256 blocks per epoch
        while (__hip_atomic_load(cnt, __ATOMIC_RELAXED, __HIP_MEMORY_SCOPE_AGENT) < target)
          __builtin_amdgcn_s_sleep(8);
        __threadfence();  // acquire: invalidate L1/L2 so remote writes are visible
      }
      __syncthreads();
      const u16* tp = Hp; Hp = Hc; Hc = (u16*)tp;
    }
  }
}

extern "C" void kernel_launch(void* const* d_in, const int* in_sizes, int n_in,
                              void* d_out, int out_size, void* d_ws, size_t ws_size,
                              hipStream_t stream) {
  const int* ids = (const int*)d_in[0];
  const int* slen = (const int*)d_in[1];
  const float* emb = (const float*)d_in[2];
  const float* Wx = (const float*)d_in[3];
  const float* bx = (const float*)d_in[4];
  const float* Wh = (const float*)d_in[5];
  const float* bh = (const float*)d_in[6];
  const float* Wout = (const float*)d_in[7];
  const float* bout = (const float*)d_in[8];
  float* out = (float*)d_out;

  char* ws = (char*)d_ws;
  const size_t oW = (size_t)LL * DD * DD * 2;  // 33,554,432 B per weight array
  u16* Wxb = (u16*)ws;
  u16* Whb = (u16*)(ws + oW);
  u16* WoT = (u16*)(ws + 2 * oW);
  const size_t oWoT = (size_t)VV * DD * 2;     // 262,144 B
  u16* HbA = (u16*)(ws + 2 * oW + oWoT);
  const size_t oHb = (size_t)LL * BB * DD * 2; // 1,048,576 B
  u16* HbB = (u16*)(ws + 2 * oW + oWoT + oHb);
  int* cnt = (int*)(ws + 2 * oW + oWoT + 2 * oHb);

  // zero state buffers + sync counter (must be 0 at each replay)
  hipMemsetAsync(ws + 2 * oW + oWoT, 0, 2 * oHb + 128, stream);

  const size_t n4 = (size_t)LL * DD * DD / 4;
  convert_w<<<dim3(4096), dim3(256), 0, stream>>>(Wx, Wxb, n4);
  convert_w<<<dim3(4096), dim3(256), 0, stream>>>(Wh, Whb, n4);
  convert_woT<<<dim3(512), dim3(256), 0, stream>>>(Wout, WoT);

  void* kp[13];
  kp[0] = (void*)&ids;  kp[1] = (void*)&slen; kp[2] = (void*)&emb;
  kp[3] = (void*)&bx;   kp[4] = (void*)&bh;
  kp[5] = (void*)&Wxb;  kp[6] = (void*)&Whb;  kp[7] = (void*)&WoT;
  kp[8] = (void*)&bout; kp[9] = (void*)&HbA;  kp[10] = (void*)&HbB;
  kp[11] = (void*)&out; kp[12] = (void*)&cnt;
  hipLaunchCooperativeKernel((const void*)persist, dim3(256), dim3(512), kp, 0, stream);
}

// Round 4
// 20898.331 us; speedup vs baseline: 3.8670x; 1.4431x over previous
//
#include <hip/hip_runtime.h>
#include <hip/hip_bf16.h>

#define TT 512
#define BB 64
#define DD 2048
#define LL 4
#define VV 64

typedef unsigned short u16;
typedef unsigned int u32;
typedef __attribute__((ext_vector_type(8))) short s16x8;
typedef __attribute__((ext_vector_type(4))) float f32x4;

#define MFMA(a, b, c) __builtin_amdgcn_mfma_f32_16x16x32_bf16((a), (b), (c), 0, 0, 0)

__device__ inline u16 f2b(float f) {
  u32 u = __builtin_bit_cast(u32, f);
  u32 r = (u + 0x7fffu + ((u >> 16) & 1u)) >> 16;
  return (u16)r;
}
__device__ inline float b2f(u16 b) {
  u32 u = ((u32)b) << 16;
  return __builtin_bit_cast(float, u);
}

__global__ __launch_bounds__(256) void convert_w(const float* __restrict__ src,
                                                 u16* __restrict__ dst, size_t n4) {
  size_t i = (size_t)blockIdx.x * 256 + threadIdx.x;
  size_t stride = (size_t)gridDim.x * 256;
  for (size_t j = i; j < n4; j += stride) {
    float4 f = ((const float4*)src)[j];
    ushort4 o;
    o.x = f2b(f.x); o.y = f2b(f.y); o.z = f2b(f.z); o.w = f2b(f.w);
    ((ushort4*)dst)[j] = o;
  }
}

// WoutT[v][k] = bf16(Wout[k][v]);  Wout is [2048][64] fp32
__global__ __launch_bounds__(256) void convert_woT(const float* __restrict__ Wout,
                                                   u16* __restrict__ WoT) {
  int g = blockIdx.x * 256 + threadIdx.x;  // 131072 total
  int v = g >> 11, k = g & 2047;
  WoT[(size_t)v * DD + k] = f2b(Wout[(size_t)k * VV + v]);
}

// Persistent kernel: 256 blocks x 512 threads, 1 block/CU.
// Block bid -> layer l = bid>>6, columns col0 = (bid&63)*32.
// 8 waves: ch = w&1 (16-col half), ks = w>>1 (k-slice of 512).
// Weights pinned in VGPRs via opaque asm (32 x s16x8 = 128 VGPRs/lane).
__global__ __launch_bounds__(512, 2)
void persist(const int* __restrict__ ids, const int* __restrict__ slen,
             const float* __restrict__ bxp, const float* __restrict__ bhp,
             const u16* __restrict__ embb,
             const u16* __restrict__ Wxb, const u16* __restrict__ Whb,
             const u16* __restrict__ WoT, const float* __restrict__ bout,
             u16* __restrict__ HbA, u16* __restrict__ HbB,
             float* __restrict__ out, int* __restrict__ sync) {
  const int tid = threadIdx.x, bid = blockIdx.x;
  const int l = bid >> 6;
  const int col0 = (bid & 63) << 5;
  const int w = tid >> 6, lane = tid & 63;
  const int ch = w & 1, ks = w >> 1;
  const int lr = lane & 15, q = lane >> 4;
  const int ncol = col0 + (ch << 4) + lr;
  const int kb0 = (ks << 9) + (q << 3);  // ks*512 + q*8

  // ---- load weight fragments into VGPRs (once), then pin as opaque ----
  s16x8 wx[16], wh[16];
  {
    const u16* p0 = Wxb + ((size_t)l * DD + ncol) * DD + kb0;
    const u16* p1 = Whb + ((size_t)l * DD + ncol) * DD + kb0;
#pragma unroll
    for (int kt = 0; kt < 16; ++kt) {
      wx[kt] = *(const s16x8*)(p0 + (kt << 5));
      wh[kt] = *(const s16x8*)(p1 + (kt << 5));
    }
  }
#pragma unroll
  for (int kt = 0; kt < 16; ++kt) {
    asm("" : "+v"(wx[kt]));
    asm("" : "+v"(wh[kt]));
  }

  // ---- out-proj assignment: 4 batch rows x 4 vocab cols per block ----
  const int opo = tid >> 5, ln32 = tid & 31;
  const int opb = ((bid >> 4) << 2) + (opo >> 2);
  const int opv = ((bid & 15) << 2) + (opo & 3);
  const float boutv = bout[opv];

  // ---- per-thread reduce-output precompute (4 outputs each) ----
  int rm[4], rn[4], rcol[4], rch[4], rslen[4];
  float bsum[4];
#pragma unroll
  for (int s = 0; s < 4; ++s) {
    int o = tid + (s << 9);
    int cch = o >> 10, rem = o & 1023;
    rm[s] = rem >> 4;
    rn[s] = rem & 15;
    rch[s] = cch;
    rcol[s] = col0 + (cch << 4) + rn[s];
    bsum[s] = bxp[l * DD + rcol[s]] + bhp[l * DD + rcol[s]];
    rslen[s] = slen[rm[s]];
  }

  __shared__ float part[8][64][17];
  __shared__ int sids[64];

  const u16* Hp = HbA;
  u16* Hc = HbB;
  int ep = 0;

  for (int t = 0; t <= TT; ++t) {
    if (t < TT) {
      if (tid < BB) sids[tid] = ids[tid * TT + t];
      __syncthreads();

      const u16* hsrc = Hp + (size_t)l * BB * DD;
      const u16* xs0, *xs1, *xs2, *xs3;
      if (l == 0) {
        xs0 = embb + (size_t)sids[lr] * DD;
        xs1 = embb + (size_t)sids[lr + 16] * DD;
        xs2 = embb + (size_t)sids[lr + 32] * DD;
        xs3 = embb + (size_t)sids[lr + 48] * DD;
      } else {
        const u16* xsrc = Hp + (size_t)(l - 1) * BB * DD;
        xs0 = xsrc + (size_t)lr * DD;
        xs1 = xsrc + (size_t)(lr + 16) * DD;
        xs2 = xsrc + (size_t)(lr + 32) * DD;
        xs3 = xsrc + (size_t)(lr + 48) * DD;
      }
      const u16* hs0 = hsrc + (size_t)lr * DD;
      const u16* hs1 = hsrc + (size_t)(lr + 16) * DD;
      const u16* hs2 = hsrc + (size_t)(lr + 32) * DD;
      const u16* hs3 = hsrc + (size_t)(lr + 48) * DD;

      f32x4 acc0 = {0, 0, 0, 0}, acc1 = {0, 0, 0, 0};
      f32x4 acc2 = {0, 0, 0, 0}, acc3 = {0, 0, 0, 0};
#pragma unroll
      for (int kt = 0; kt < 16; ++kt) {
        const int kk = kb0 + (kt << 5);
        s16x8 ax0 = *(const s16x8*)(xs0 + kk);
        s16x8 ax1 = *(const s16x8*)(xs1 + kk);
        s16x8 ax2 = *(const s16x8*)(xs2 + kk);
        s16x8 ax3 = *(const s16x8*)(xs3 + kk);
        s16x8 ah0 = *(const s16x8*)(hs0 + kk);
        s16x8 ah1 = *(const s16x8*)(hs1 + kk);
        s16x8 ah2 = *(const s16x8*)(hs2 + kk);
        s16x8 ah3 = *(const s16x8*)(hs3 + kk);
        acc0 = MFMA(ax0, wx[kt], acc0); acc0 = MFMA(ah0, wh[kt], acc0);
        acc1 = MFMA(ax1, wx[kt], acc1); acc1 = MFMA(ah1, wh[kt], acc1);
        acc2 = MFMA(ax2, wx[kt], acc2); acc2 = MFMA(ah2, wh[kt], acc2);
        acc3 = MFMA(ax3, wx[kt], acc3); acc3 = MFMA(ah3, wh[kt], acc3);
      }
      // partials to LDS: part[w][m][n], m = mt*16 + q*4 + i, n = lr
#pragma unroll
      for (int i = 0; i < 4; ++i) {
        part[w][(q << 2) + i][lr] = acc0[i];
        part[w][16 + (q << 2) + i][lr] = acc1[i];
        part[w][32 + (q << 2) + i][lr] = acc2[i];
        part[w][48 + (q << 2) + i][lr] = acc3[i];
      }
      __syncthreads();
      // k-reduction + bias + tanh + mask + state write (4 outputs/thread)
#pragma unroll
      for (int s = 0; s < 4; ++s) {
        const int cch = rch[s], m = rm[s], n = rn[s];
        float sum = part[cch][m][n] + part[cch + 2][m][n] +
                    part[cch + 4][m][n] + part[cch + 6][m][n] + bsum[s];
        float hv = tanhf(sum);
        size_t idx = ((size_t)l * BB + m) * DD + rcol[s];
        Hc[idx] = (t < rslen[s]) ? f2b(hv) : Hp[idx];
      }
    }

    // output projection for step t-1 (reads Hp = state t-1)
    if (t > 0) {
      const u16* h3 = Hp + (size_t)3 * BB * DD;
      const u16* hp = h3 + (size_t)opb * DD + (ln32 << 6);
      const u16* wp = WoT + (size_t)opv * DD + (ln32 << 6);
      float sacc = 0.f;
#pragma unroll
      for (int j = 0; j < 64; j += 8) {
        s16x8 hv8 = *(const s16x8*)(hp + j);
        s16x8 wv8 = *(const s16x8*)(wp + j);
#pragma unroll
        for (int e = 0; e < 8; ++e)
          sacc = fmaf(b2f((u16)hv8[e]), b2f((u16)wv8[e]), sacc);
      }
#pragma unroll
      for (int d = 16; d > 0; d >>= 1) sacc += __shfl_xor(sacc, d, 64);
      if (ln32 == 0)
        out[((size_t)opb * TT + (t - 1)) * VV + opv] = sacc + boutv;
    }

    // hierarchical grid barrier (monotonic epochs), then swap state buffers
    if (t < TT) {
      ++ep;
      __syncthreads();
      if (tid == 0) {
        // level 1: 8 spread arrival counters, 32 blocks each (128 B apart)
        __hip_atomic_fetch_add(&sync[(bid & 7) * 32], 1, __ATOMIC_RELEASE,
                               __HIP_MEMORY_SCOPE_AGENT);
        if (bid < 8) {
          while (__hip_atomic_load(&sync[bid * 32], __ATOMIC_RELAXED,
                                   __HIP_MEMORY_SCOPE_AGENT) < 32 * ep)
            __builtin_amdgcn_s_sleep(1);
          __hip_atomic_fetch_add(&sync[256], 1, __ATOMIC_ACQ_REL,
                                 __HIP_MEMORY_SCOPE_AGENT);
        }
        if (bid == 0) {
          while (__hip_atomic_load(&sync[256], __ATOMIC_RELAXED,
                                   __HIP_MEMORY_SCOPE_AGENT) < 8 * ep)
            __builtin_amdgcn_s_sleep(1);
          __hip_atomic_store(&sync[288], ep, __ATOMIC_RELEASE,
                             __HIP_MEMORY_SCOPE_AGENT);
        }
        while (__hip_atomic_load(&sync[288], __ATOMIC_RELAXED,
                                 __HIP_MEMORY_SCOPE_AGENT) < ep)
          __builtin_amdgcn_s_sleep(2);
        // acquire: make remote state writes visible (invalidates L1/L2 once)
        __hip_atomic_load(&sync[288], __ATOMIC_ACQUIRE, __HIP_MEMORY_SCOPE_AGENT);
      }
      __syncthreads();
      const u16* tp = Hp; Hp = Hc; Hc = (u16*)tp;
    }
  }
}

extern "C" void kernel_launch(void* const* d_in, const int* in_sizes, int n_in,
                              void* d_out, int out_size, void* d_ws, size_t ws_size,
                              hipStream_t stream) {
  const int* ids = (const int*)d_in[0];
  const int* slen = (const int*)d_in[1];
  const float* emb = (const float*)d_in[2];
  const float* Wx = (const float*)d_in[3];
  const float* bx = (const float*)d_in[4];
  const float* Wh = (const float*)d_in[5];
  const float* bh = (const float*)d_in[6];
  const float* Wout = (const float*)d_in[7];
  const float* bout = (const float*)d_in[8];
  float* out = (float*)d_out;

  char* ws = (char*)d_ws;
  const size_t oW = (size_t)LL * DD * DD * 2;   // 33,554,432 B per weight array
  const size_t oWoT = (size_t)VV * DD * 2;      // 262,144 B
  const size_t oEmb = (size_t)VV * DD * 2;      // 262,144 B
  const size_t oHb = (size_t)LL * BB * DD * 2;  // 1,048,576 B
  u16* Wxb = (u16*)ws;
  u16* Whb = (u16*)(ws + oW);
  u16* WoT = (u16*)(ws + 2 * oW);
  u16* embb = (u16*)(ws + 2 * oW + oWoT);
  u16* HbA = (u16*)(ws + 2 * oW + oWoT + oEmb);
  u16* HbB = (u16*)(ws + 2 * oW + oWoT + oEmb + oHb);
  int* sync = (int*)(ws + 2 * oW + oWoT + oEmb + 2 * oHb);

  // zero state buffers + sync counters (must be 0 at each replay)
  hipMemsetAsync(ws + 2 * oW + oWoT + oEmb, 0, 2 * oHb + 2048, stream);

  const size_t n4 = (size_t)LL * DD * DD / 4;
  convert_w<<<dim3(4096), dim3(256), 0, stream>>>(Wx, Wxb, n4);
  convert_w<<<dim3(4096), dim3(256), 0, stream>>>(Wh, Whb, n4);
  convert_w<<<dim3(128), dim3(256), 0, stream>>>(emb, embb, (size_t)VV * DD / 4);
  convert_woT<<<dim3(512), dim3(256), 0, stream>>>(Wout, WoT);

  void* kp[13];
  kp[0] = (void*)&ids;  kp[1] = (void*)&slen;
  kp[2] = (void*)&bx;   kp[3] = (void*)&bh;   kp[4] = (void*)&embb;
  kp[5] = (void*)&Wxb;  kp[6] = (void*)&Whb;  kp[7] = (void*)&WoT;
  kp[8] = (void*)&bout; kp[9] = (void*)&HbA;  kp[10] = (void*)&HbB;
  kp[11] = (void*)&out; kp[12] = (void*)&sync;
  hipLaunchCooperativeKernel((const void*)persist, dim3(256), dim3(512), kp, 0, stream);
}

// Round 5
// 17910.536 us; speedup vs baseline: 4.5120x; 1.1668x over previous
//
#include <hip/hip_runtime.h>
#include <hip/hip_bf16.h>

#define TT 512
#define BB 64
#define DD 2048
#define LL 4
#define VV 64

typedef unsigned short u16;
typedef unsigned int u32;
typedef unsigned long long u64;
typedef __attribute__((ext_vector_type(8))) short s16x8;
typedef __attribute__((ext_vector_type(4))) float f32x4;

#define MFMA(a, b, c) __builtin_amdgcn_mfma_f32_16x16x32_bf16((a), (b), (c), 0, 0, 0)

__device__ inline u16 f2b(float f) {
  u32 u = __builtin_bit_cast(u32, f);
  u32 r = (u + 0x7fffu + ((u >> 16) & 1u)) >> 16;
  return (u16)r;
}
__device__ inline float b2f(u16 b) {
  u32 u = ((u32)b) << 16;
  return __builtin_bit_cast(float, u);
}

__global__ __launch_bounds__(256) void convert_w(const float* __restrict__ src,
                                                 u16* __restrict__ dst, size_t n4) {
  size_t i = (size_t)blockIdx.x * 256 + threadIdx.x;
  size_t stride = (size_t)gridDim.x * 256;
  for (size_t j = i; j < n4; j += stride) {
    float4 f = ((const float4*)src)[j];
    ushort4 o;
    o.x = f2b(f.x); o.y = f2b(f.y); o.z = f2b(f.z); o.w = f2b(f.w);
    ((ushort4*)dst)[j] = o;
  }
}

// WoutT[v][k] = bf16(Wout[k][v]);  Wout is [2048][64] fp32
__global__ __launch_bounds__(256) void convert_woT(const float* __restrict__ Wout,
                                                   u16* __restrict__ WoT) {
  int g = blockIdx.x * 256 + threadIdx.x;  // 131072 total
  int v = g >> 11, k = g & 2047;
  WoT[(size_t)v * DD + k] = f2b(Wout[(size_t)k * VV + v]);
}

// Persistent kernel: 256 blocks x 512 threads, 1 block/CU.
// Block bid -> layer l = bid>>6, columns col0 = (bid&63)*32.
// 8 waves: ch = w&1 (16-col half), ks = w>>1 (k-slice of 512).
// Weights pinned in VGPR/AGPR via opaque asm (32 x s16x8 = 128 regs/lane).
// State stores are write-through (SYSTEM-scope relaxed) -> barrier needs no
// RELEASE fences (no L2 writeback storm); one ACQUIRE inv per block per step.
__global__ __launch_bounds__(512, 2)
void persist(const int* __restrict__ ids, const int* __restrict__ slen,
             const float* __restrict__ bxp, const float* __restrict__ bhp,
             const u16* __restrict__ embb,
             const u16* __restrict__ Wxb, const u16* __restrict__ Whb,
             const u16* __restrict__ WoT, const float* __restrict__ bout,
             u16* b0, u16* b1, u16* b2,
             float* __restrict__ out, int* sync) {
  const int tid = threadIdx.x, bid = blockIdx.x;
  const int l = bid >> 6;
  const int col0 = (bid & 63) << 5;
  const int w = tid >> 6, lane = tid & 63;
  const int ch = w & 1, ks = w >> 1;
  const int lr = lane & 15, q = lane >> 4;
  const int ncol = col0 + (ch << 4) + lr;
  const int kb0 = (ks << 9) + (q << 3);  // ks*512 + q*8

  // ---- load weight fragments (once), pin as opaque ----
  s16x8 wx[16], wh[16];
  {
    const u16* p0 = Wxb + ((size_t)l * DD + ncol) * DD + kb0;
    const u16* p1 = Whb + ((size_t)l * DD + ncol) * DD + kb0;
#pragma unroll
    for (int kt = 0; kt < 16; ++kt) {
      wx[kt] = *(const s16x8*)(p0 + (kt << 5));
      wh[kt] = *(const s16x8*)(p1 + (kt << 5));
    }
  }
#pragma unroll
  for (int kt = 0; kt < 16; ++kt) {
    asm("" : "+v"(wx[kt]));
    asm("" : "+v"(wh[kt]));
  }

  // ---- out-proj assignment: 4 batch rows x 4 vocab cols per block ----
  const int opo = tid >> 5, ln32 = tid & 31;
  const int opb = ((bid >> 4) << 2) + (opo >> 2);
  const int opv = ((bid & 15) << 2) + (opo & 3);
  const float boutv = bout[opv];

  // ---- reduce-quad mapping: each thread owns 4 adjacent cols of one row ----
  const int cch = tid >> 8;            // 0/1: 16-col half
  const int qm = (tid >> 2) & 63;      // batch row
  const int nq = (tid & 3) << 2;       // col-quad within half
  const int qcol = col0 + (cch << 4) + nq;
  float qb[4];
#pragma unroll
  for (int e = 0; e < 4; ++e)
    qb[e] = bxp[l * DD + qcol + e] + bhp[l * DD + qcol + e];
  const int qlen = slen[qm];

  __shared__ __align__(16) float part[8][64][20];
  __shared__ int sids[64];

  const u16* Hp = b2;  // read buffer (state t-1); b2 zeroed = H0
  u16* Hc = b0;        // write buffer (state t)
  u16* Ho = b1;        // oldest, next write target

  for (int t = 0; t <= TT; ++t) {
    if (t < TT) {
      if (tid < BB) sids[tid] = ids[tid * TT + t];
      __syncthreads();

      const u16* hsrc = Hp + (size_t)l * BB * DD;
      const u16 *xs0, *xs1, *xs2, *xs3;
      if (l == 0) {
        xs0 = embb + (size_t)sids[lr] * DD;
        xs1 = embb + (size_t)sids[lr + 16] * DD;
        xs2 = embb + (size_t)sids[lr + 32] * DD;
        xs3 = embb + (size_t)sids[lr + 48] * DD;
      } else {
        const u16* xsrc = Hp + (size_t)(l - 1) * BB * DD;
        xs0 = xsrc + (size_t)lr * DD;
        xs1 = xsrc + (size_t)(lr + 16) * DD;
        xs2 = xsrc + (size_t)(lr + 32) * DD;
        xs3 = xsrc + (size_t)(lr + 48) * DD;
      }
      const u16* hs0 = hsrc + (size_t)lr * DD;
      const u16* hs1 = hsrc + (size_t)(lr + 16) * DD;
      const u16* hs2 = hsrc + (size_t)(lr + 32) * DD;
      const u16* hs3 = hsrc + (size_t)(lr + 48) * DD;

      f32x4 acc0 = {0, 0, 0, 0}, acc1 = {0, 0, 0, 0};
      f32x4 acc2 = {0, 0, 0, 0}, acc3 = {0, 0, 0, 0};
#pragma unroll
      for (int kt = 0; kt < 16; ++kt) {
        const int kk = kb0 + (kt << 5);
        s16x8 ax0 = *(const s16x8*)(xs0 + kk);
        s16x8 ax1 = *(const s16x8*)(xs1 + kk);
        s16x8 ax2 = *(const s16x8*)(xs2 + kk);
        s16x8 ax3 = *(const s16x8*)(xs3 + kk);
        s16x8 ah0 = *(const s16x8*)(hs0 + kk);
        s16x8 ah1 = *(const s16x8*)(hs1 + kk);
        s16x8 ah2 = *(const s16x8*)(hs2 + kk);
        s16x8 ah3 = *(const s16x8*)(hs3 + kk);
        acc0 = MFMA(ax0, wx[kt], acc0); acc0 = MFMA(ah0, wh[kt], acc0);
        acc1 = MFMA(ax1, wx[kt], acc1); acc1 = MFMA(ah1, wh[kt], acc1);
        acc2 = MFMA(ax2, wx[kt], acc2); acc2 = MFMA(ah2, wh[kt], acc2);
        acc3 = MFMA(ax3, wx[kt], acc3); acc3 = MFMA(ah3, wh[kt], acc3);
      }
#pragma unroll
      for (int i = 0; i < 4; ++i) {
        part[w][(q << 2) + i][lr] = acc0[i];
        part[w][16 + (q << 2) + i][lr] = acc1[i];
        part[w][32 + (q << 2) + i][lr] = acc2[i];
        part[w][48 + (q << 2) + i][lr] = acc3[i];
      }
      __syncthreads();
      // k-reduce quad + bias + tanh + mask + packed write-through store
      {
        f32x4 p0 = *(const f32x4*)&part[cch][qm][nq];
        f32x4 p1 = *(const f32x4*)&part[cch + 2][qm][nq];
        f32x4 p2 = *(const f32x4*)&part[cch + 4][qm][nq];
        f32x4 p3 = *(const f32x4*)&part[cch + 6][qm][nq];
        f32x4 sum = ((p0 + p1) + p2) + p3;
        float h0 = tanhf(sum[0] + qb[0]);
        float h1 = tanhf(sum[1] + qb[1]);
        float h2 = tanhf(sum[2] + qb[2]);
        float h3 = tanhf(sum[3] + qb[3]);
        size_t idx = ((size_t)l * BB + qm) * DD + qcol;
        u64 pk = (u64)f2b(h0) | ((u64)f2b(h1) << 16) |
                 ((u64)f2b(h2) << 32) | ((u64)f2b(h3) << 48);
        u64 val = (t < qlen) ? pk : *(const u64*)(Hp + idx);
        __hip_atomic_store((u64*)(Hc + idx), val, __ATOMIC_RELAXED,
                           __HIP_MEMORY_SCOPE_SYSTEM);
      }
      asm volatile("s_waitcnt vmcnt(0)" ::: "memory");  // stores at coherence pt
    }
    __syncthreads();  // all waves drained

    const int ep = t + 1;
    // barrier arrival (all relaxed; no cache ops)
    if (t < TT && tid == 0) {
      int old = __hip_atomic_fetch_add(&sync[(bid & 7) << 5], 1,
                                       __ATOMIC_RELAXED, __HIP_MEMORY_SCOPE_AGENT);
      if (((old + 1) & 31) == 0) {
        int rold = __hip_atomic_fetch_add(&sync[256], 1, __ATOMIC_RELAXED,
                                          __HIP_MEMORY_SCOPE_AGENT);
        if (((rold + 1) & 7) == 0)
          __hip_atomic_store(&sync[288], ep, __ATOMIC_RELAXED,
                             __HIP_MEMORY_SCOPE_AGENT);
      }
    }

    // output projection for step t-1 (reads Hp; safe under triple-buffering,
    // overlapped with other blocks' barrier arrivals)
    if (t > 0) {
      const u16* h3p = Hp + (size_t)3 * BB * DD;
      const u16* hp = h3p + (size_t)opb * DD + (ln32 << 6);
      const u16* wp = WoT + (size_t)opv * DD + (ln32 << 6);
      float sacc = 0.f;
#pragma unroll
      for (int j = 0; j < 64; j += 8) {
        s16x8 hv8 = *(const s16x8*)(hp + j);
        s16x8 wv8 = *(const s16x8*)(wp + j);
#pragma unroll
        for (int e = 0; e < 8; ++e)
          sacc = fmaf(b2f((u16)hv8[e]), b2f((u16)wv8[e]), sacc);
      }
#pragma unroll
      for (int d = 16; d > 0; d >>= 1) sacc += __shfl_xor(sacc, d, 64);
      if (ln32 == 0)
        out[((size_t)opb * TT + (t - 1)) * VV + opv] = sacc + boutv;
    }

    // barrier wait + single acquire (inv) per block, then rotate buffers
    if (t < TT) {
      if (tid == 0) {
        while (__hip_atomic_load(&sync[288], __ATOMIC_RELAXED,
                                 __HIP_MEMORY_SCOPE_AGENT) < ep)
          __builtin_amdgcn_s_sleep(2);
        __hip_atomic_load(&sync[288], __ATOMIC_ACQUIRE, __HIP_MEMORY_SCOPE_AGENT);
      }
      __syncthreads();
      const u16* newHp = Hc;
      u16* newHc = Ho;
      Ho = (u16*)Hp;
      Hp = newHp;
      Hc = newHc;
    }
  }
}

extern "C" void kernel_launch(void* const* d_in, const int* in_sizes, int n_in,
                              void* d_out, int out_size, void* d_ws, size_t ws_size,
                              hipStream_t stream) {
  const int* ids = (const int*)d_in[0];
  const int* slen = (const int*)d_in[1];
  const float* emb = (const float*)d_in[2];
  const float* Wx = (const float*)d_in[3];
  const float* bx = (const float*)d_in[4];
  const float* Wh = (const float*)d_in[5];
  const float* bh = (const float*)d_in[6];
  const float* Wout = (const float*)d_in[7];
  const float* bout = (const float*)d_in[8];
  float* out = (float*)d_out;

  char* ws = (char*)d_ws;
  const size_t oW = (size_t)LL * DD * DD * 2;   // 33,554,432 B per weight array
  const size_t oWoT = (size_t)VV * DD * 2;      // 262,144 B
  const size_t oEmb = (size_t)VV * DD * 2;      // 262,144 B
  const size_t oHb = (size_t)LL * BB * DD * 2;  // 1,048,576 B
  u16* Wxb = (u16*)ws;
  u16* Whb = (u16*)(ws + oW);
  u16* WoT = (u16*)(ws + 2 * oW);
  u16* embb = (u16*)(ws + 2 * oW + oWoT);
  u16* b0 = (u16*)(ws + 2 * oW + oWoT + oEmb);
  u16* b1 = (u16*)(ws + 2 * oW + oWoT + oEmb + oHb);
  u16* b2 = (u16*)(ws + 2 * oW + oWoT + oEmb + 2 * oHb);
  int* sync = (int*)(ws + 2 * oW + oWoT + oEmb + 3 * oHb);

  // zero all state buffers + sync counters (graph replay re-runs this)
  hipMemsetAsync(ws + 2 * oW + oWoT + oEmb, 0, 3 * oHb + 4096, stream);

  const size_t n4 = (size_t)LL * DD * DD / 4;
  convert_w<<<dim3(4096), dim3(256), 0, stream>>>(Wx, Wxb, n4);
  convert_w<<<dim3(4096), dim3(256), 0, stream>>>(Wh, Whb, n4);
  convert_w<<<dim3(128), dim3(256), 0, stream>>>(emb, embb, (size_t)VV * DD / 4);
  convert_woT<<<dim3(512), dim3(256), 0, stream>>>(Wout, WoT);

  void* kp[14];
  kp[0] = (void*)&ids;  kp[1] = (void*)&slen;
  kp[2] = (void*)&bx;   kp[3] = (void*)&bh;   kp[4] = (void*)&embb;
  kp[5] = (void*)&Wxb;  kp[6] = (void*)&Whb;  kp[7] = (void*)&WoT;
  kp[8] = (void*)&bout; kp[9] = (void*)&b0;   kp[10] = (void*)&b1;
  kp[11] = (void*)&b2;  kp[12] = (void*)&out; kp[13] = (void*)&sync;
  hipLaunchCooperativeKernel((const void*)persist, dim3(256), dim3(512), kp, 0, stream);
}